// Round 17
// baseline (128.755 us; speedup 1.0000x reference)
//
#include <hip/hip_runtime.h>
#include <math.h>

// ---------------------------------------------------------------------------
// A3C_LSTM_GA forward, batch=1.  R17 = R10 (best, 125.7us) + dual-pipe split:
// R10 streams all 384KB/step of f16 weights through L2->L1 (238 GB/s ceiling,
// 1.65us/step) while the LDS pipe idles.  Minimal diff: row rho=5 of each
// octet (4 fragments/thread, 64KB total) is staged ONCE into LDS and read
// from there each step; the other 20 fragments keep R10's proven remat
// stream (L2 drops to 320KB/step = 1.37us).  Everything else byte-identical.
//  K1 a3c_pre (582 blocks x 256): b0 img MLP | b1-4 gates_h | b5 head-bias |
//     b6-197 gi f32 | b198-581 weight fragment pack (R10 layout, unchanged)
//  K2 a3c_scan (1 block x 1024): scan + attention/fuse/lin tail
//  K3 a3c_post (4 blocks x 256): LSTM -> h/c -> head atomicAdd partials
// ---------------------------------------------------------------------------

typedef __fp16 h2 __attribute__((ext_vector_type(2)));
typedef __fp16 h8 __attribute__((ext_vector_type(8)));
typedef float  f4 __attribute__((ext_vector_type(4)));

// ws float offsets
#define WS_IMG    0        // 128
#define WS_GATESH 128      // 1024
#define WS_FUSED  1152     // 256
#define WS_GI     1408     // 64*768 f32                       end 50560
#define WS_REGW   50560    // 98304 float slots (196608 f16)   end 148864

__device__ __forceinline__ float dot4(const float4 a, const float4 b){
  return a.x*b.x + a.y*b.y + a.z*b.z + a.w*b.w;
}
__device__ __forceinline__ float sigm(float x){ return 1.f/(1.f+expf(-x)); }

#define P0(v) __builtin_shufflevector(v,v,0,1)
#define P1(v) __builtin_shufflevector(v,v,2,3)
#define P2(v) __builtin_shufflevector(v,v,4,5)
#define P3(v) __builtin_shufflevector(v,v,6,7)
#define PK(a,b) __builtin_amdgcn_cvt_pkrtz(a,b)
#define FD(w,e,acc) __builtin_amdgcn_fdot2(w,e,acc,false)

// ------------------------------------------------------------------- K1
__global__ __launch_bounds__(256) void a3c_pre(
    const float* __restrict__ x,
    const float* __restrict__ i1w, const float* __restrict__ i1b,
    const float* __restrict__ i2w, const float* __restrict__ i2b,
    const float* __restrict__ i3w, const float* __restrict__ i3b,
    const float* __restrict__ hx,  const float* __restrict__ lwh,
    const float* __restrict__ lbh,
    const int*   __restrict__ tx,  const float* __restrict__ temb,
    const float* __restrict__ cw,  const float* __restrict__ cb,
    const float* __restrict__ acw, const float* __restrict__ acb,
    const int*   __restrict__ inst, const float* __restrict__ emb,
    const float* __restrict__ gwi,  const float* __restrict__ gbi,
    const float* __restrict__ gwh,
    float* __restrict__ ws, float* __restrict__ out)
{
  const int b = blockIdx.x;
  const int t = threadIdx.x;

  if (b == 0) {
    // image MLP 400 -> 128 -> 128 -> 128
    __shared__ __align__(16) float x_lds[400];
    __shared__ __align__(16) float h1[128];
    __shared__ __align__(16) float h2s[128];
    x_lds[t] = x[t];
    if (t < 144) x_lds[256+t] = x[256+t];
    __syncthreads();
    {
      const int o = t>>1, half = t&1;
      const float4* wr = (const float4*)(i1w + o*400 + half*200);
      const float4* xr = (const float4*)(x_lds + half*200);
      float acc = 0.f;
      #pragma unroll 5
      for (int k=0;k<50;++k) acc += dot4(wr[k], xr[k]);
      acc += __shfl_down(acc, 1, 2);
      if (half == 0) h1[o] = fmaxf(acc + i1b[o], 0.f);
    }
    __syncthreads();
    if (t < 128){
      const float4* wr = (const float4*)(i2w + t*128);
      const float4* h4 = (const float4*)h1;
      float acc = i2b[t];
      #pragma unroll 8
      for (int k=0;k<32;++k) acc += dot4(wr[k], h4[k]);
      h2s[t] = fmaxf(acc, 0.f);
    }
    __syncthreads();
    if (t < 128){
      const float4* wr = (const float4*)(i3w + t*128);
      const float4* h4 = (const float4*)h2s;
      float acc = i3b[t];
      #pragma unroll 8
      for (int k=0;k<32;++k) acc += dot4(wr[k], h4[k]);
      ws[WS_IMG + t] = fmaxf(acc, 0.f);
    }

  } else if (b <= 4) {
    // gates_h = hx @ lstm_wh.T + lstm_bh
    __shared__ __align__(16) float hx_lds[256];
    hx_lds[t] = hx[t];
    __syncthreads();
    const int R = (b-1)*256 + t;
    const float4* wr = (const float4*)(lwh + R*256);
    const float4* h4 = (const float4*)hx_lds;
    float acc = lbh[R];
    #pragma unroll 8
    for (int k=0;k<64;++k) acc += dot4(wr[k], h4[k]);
    ws[WS_GATESH + R] = acc;

  } else if (b == 5) {
    // out[0..4] = bias + time-embedding partial of heads
    if (t < 64){
      float tv = 0.f;
      if (t < 32) tv = temb[tx[0]*32 + t];
      #pragma unroll
      for (int o=0;o<5;++o){
        const float* wrow = (o==0) ? cw : (acw + (o-1)*288);
        float pr = (t < 32) ? tv*wrow[256+t] : 0.f;
        #pragma unroll
        for (int off=16; off; off>>=1) pr += __shfl_down(pr, off, 32);
        if (t == 0) out[o] = pr + ((o==0) ? cb[0] : acb[o-1]);
      }
    }

  } else if (b < 198) {
    // gi[s][row] (f32): 192 blocks x 256 = 49152 = 64*768
    const int idx = (b-6)*256 + t;
    const int s = idx / 768;
    const int r = idx - s*768;
    const float4* wr = (const float4*)(gwi + r*32);
    const float4* er = (const float4*)(emb + inst[s]*32);
    float acc = gbi[r];
    #pragma unroll
    for (int k=0;k<8;++k) acc += dot4(wr[k], er[k]);
    ws[WS_GI + idx] = acc;

  } else {
    // regw: 384 blocks x 256 = 98304 h2 = 196608 f16, per-thread order:
    // thread tt = (octet o = tt>>3, lane i = tt&7) : rows 6o+rho (rho 0..5),
    // cols 32i + 8c + el (c 0..3, el 0..7); fragment index rho*4+c
    const int d = (b-198)*256 + t;      // h2 index
    const int e = d << 1;               // f16 index
    const int tt = e / 192;
    int rem = e - tt*192;
    const int rho = rem >> 5; rem &= 31;
    const int c = rem >> 3;
    const int el = rem & 7;
    const int row = 6*(tt>>3) + rho;
    const int col = ((tt&7)<<5) + (c<<3) + el;
    ((h2*)(ws + WS_REGW))[d] = PK(gwh[row*256+col], gwh[row*256+col+1]);
  }
}

// ------------------------------------------------------------------- K2
__global__ __attribute__((amdgpu_flat_work_group_size(1024,1024)))
void a3c_scan(
    const float* __restrict__ gbh,
    const float* __restrict__ aw,  const float* __restrict__ ab,
    const float* __restrict__ lnw, const float* __restrict__ lnb,
    float* __restrict__ ws)
{
  const int t = threadIdx.x;
  const int o = t >> 3, i = t & 7;

  __shared__ __align__(16) __fp16 h16[256];
  __shared__ float h32[256];
  __shared__ float pp[768*9];          // partials [row][9] (pad vs conflicts)
  __shared__ float bhl[768];
  __shared__ float gil[2][768];
  __shared__ __align__(16) float f0[128];
  __shared__ __align__(16) f4 lwf[4096];   // 64 KB: row rho=5 frags, [c][t]

  if (t < 768){ bhl[t] = gbh[t]; gil[0][t] = ws[WS_GI + t]; }
  if (t < 256){ h16[t] = (__fp16)0.f; h32[t] = 0.f; }

  // 20 pinned L2-stream fragments (rows rho 0..4) + stage rho=5 into LDS
  const f4* rw = (const f4*)(ws + WS_REGW) + t*24;
  f4 W00=rw[0],  W01=rw[1],  W02=rw[2],  W03=rw[3];
  f4 W10=rw[4],  W11=rw[5],  W12=rw[6],  W13=rw[7];
  f4 W20=rw[8],  W21=rw[9],  W22=rw[10], W23=rw[11];
  f4 W30=rw[12], W31=rw[13], W32=rw[14], W33=rw[15];
  f4 W40=rw[16], W41=rw[17], W42=rw[18], W43=rw[19];
  lwf[0*1024 + t] = rw[20];
  lwf[1*1024 + t] = rw[21];
  lwf[2*1024 + t] = rw[22];
  lwf[3*1024 + t] = rw[23];
  #define PIN(v) asm volatile("" : "+v"(v))
  PIN(W00);PIN(W01);PIN(W02);PIN(W03);PIN(W10);PIN(W11);PIN(W12);PIN(W13);
  PIN(W20);PIN(W21);PIN(W22);PIN(W23);PIN(W30);PIN(W31);PIN(W32);PIN(W33);
  PIN(W40);PIN(W41);PIN(W42);PIN(W43);
  #undef PIN
  __syncthreads();

  const int pbase = o*6;
  int cur = 0;
  for (int s=0; s<64; ++s){
    float gnx = 0.f;
    if (t < 768) gnx = ws[WS_GI + ((s<63)?(s+1):s)*768 + t];

    float a0=0.f,a1=0.f,a2=0.f,a3=0.f,a4=0.f,a5=0.f;
    #define CHUNK(c) { \
      const h8 hv = *(const h8*)(h16 + (i<<5) + ((c)<<3)); h8 w; \
      w=__builtin_bit_cast(h8,W0##c); \
      a0=FD(P0(w),P0(hv),a0); a0=FD(P1(w),P1(hv),a0); \
      a0=FD(P2(w),P2(hv),a0); a0=FD(P3(w),P3(hv),a0); \
      w=__builtin_bit_cast(h8,W1##c); \
      a1=FD(P0(w),P0(hv),a1); a1=FD(P1(w),P1(hv),a1); \
      a1=FD(P2(w),P2(hv),a1); a1=FD(P3(w),P3(hv),a1); \
      w=__builtin_bit_cast(h8,W2##c); \
      a2=FD(P0(w),P0(hv),a2); a2=FD(P1(w),P1(hv),a2); \
      a2=FD(P2(w),P2(hv),a2); a2=FD(P3(w),P3(hv),a2); \
      w=__builtin_bit_cast(h8,W3##c); \
      a3=FD(P0(w),P0(hv),a3); a3=FD(P1(w),P1(hv),a3); \
      a3=FD(P2(w),P2(hv),a3); a3=FD(P3(w),P3(hv),a3); \
      w=__builtin_bit_cast(h8,W4##c); \
      a4=FD(P0(w),P0(hv),a4); a4=FD(P1(w),P1(hv),a4); \
      a4=FD(P2(w),P2(hv),a4); a4=FD(P3(w),P3(hv),a4); \
      w=__builtin_bit_cast(h8,lwf[(c)*1024 + t]); \
      a5=FD(P0(w),P0(hv),a5); a5=FD(P1(w),P1(hv),a5); \
      a5=FD(P2(w),P2(hv),a5); a5=FD(P3(w),P3(hv),a5); }
    CHUNK(0) CHUNK(1) CHUNK(2) CHUNK(3)
    #undef CHUNK

    pp[(pbase+0)*9+i]=a0; pp[(pbase+1)*9+i]=a1; pp[(pbase+2)*9+i]=a2;
    pp[(pbase+3)*9+i]=a3; pp[(pbase+4)*9+i]=a4; pp[(pbase+5)*9+i]=a5;
    if (t < 768) gil[cur^1][t] = gnx;
    __syncthreads();
    if (t < 256){
      const float* pr = pp + t*9;
      const float* pz = pp + (256+t)*9;
      const float* pn = pp + (512+t)*9;
      float sr=bhl[t], sz=bhl[256+t], sn=bhl[512+t];
      #pragma unroll
      for (int k=0;k<8;++k){ sr+=pr[k]; sz+=pz[k]; sn+=pn[k]; }
      const float rr = sigm(gil[cur][t]       + sr);
      const float zz = sigm(gil[cur][256 + t] + sz);
      const float nn = tanhf(gil[cur][512 + t] + rr*sn);
      const float hv = (1.f - zz)*nn + zz*h32[t];
      h32[t] = hv;
      h16[t] = (__fp16)hv;
    }
    cur ^= 1;
    __syncthreads();
  }

  // ---- attention -> fuse -> lin (h_enc == h32)
  if (t < 128){
    const float4* wr2 = (const float4*)(aw + t*256);
    const float4* h4 = (const float4*)h32;
    float acc = ab[t];
    #pragma unroll 8
    for (int k=0;k<64;++k) acc += dot4(wr2[k], h4[k]);
    f0[t] = ws[WS_IMG + t] * sigm(acc);
  }
  __syncthreads();
  if (t < 256){
    const float4* wr2 = (const float4*)(lnw + t*128);
    const float4* h4 = (const float4*)f0;
    float acc = lnb[t];
    #pragma unroll 8
    for (int k=0;k<32;++k) acc += dot4(wr2[k], h4[k]);
    ws[WS_FUSED + t] = fmaxf(acc, 0.f);
  }
}

// ------------------------------------------------------------------- K3
__global__ __launch_bounds__(256) void a3c_post(
    const float* __restrict__ lwi, const float* __restrict__ lbi,
    const float* __restrict__ cx,
    const float* __restrict__ cw,  const float* __restrict__ acw,
    float* __restrict__ ws, float* __restrict__ out)
{
  const int p = blockIdx.x;            // 0..3, owns 64 LSTM units
  const int t = threadIdx.x;
  __shared__ __align__(16) float fused_lds[256];
  __shared__ float gv[256];
  __shared__ float hh[64];
  fused_lds[t] = ws[WS_FUSED + t];
  __syncthreads();
  const int g = t>>6, ul = t&63;
  const int R = (g<<8) + p*64 + ul;
  const float4* wr = (const float4*)(lwi + R*256);
  const float4* f4p = (const float4*)fused_lds;
  float acc = ws[WS_GATESH + R] + lbi[R];
  #pragma unroll 8
  for (int k=0;k<64;++k) acc += dot4(wr[k], f4p[k]);
  gv[t] = acc;
  __syncthreads();
  if (t < 64){
    const int u2 = p*64 + t;
    const float iv = gv[t], fv = gv[64+t], gg = gv[128+t], ov = gv[192+t];
    const float c = sigm(fv)*cx[u2] + sigm(iv)*tanhf(gg);
    const float h = sigm(ov)*tanhf(c);
    out[5   + u2] = h;
    out[261 + u2] = c;
    hh[t] = h;
  }
  __syncthreads();
  if (t < 64){
    #pragma unroll
    for (int o=0;o<5;++o){
      const float* wrow = (o==0) ? cw : (acw + (o-1)*288);
      float pr = hh[t]*wrow[p*64 + t];
      #pragma unroll
      for (int off=32; off; off>>=1) pr += __shfl_down(pr, off, 64);
      if (t == 0) atomicAdd(out + o, pr);
    }
  }
}

extern "C" void kernel_launch(void* const* d_in, const int* in_sizes, int n_in,
                              void* d_out, int out_size, void* d_ws, size_t ws_size,
                              hipStream_t stream) {
  (void)in_sizes; (void)n_in; (void)out_size; (void)ws_size;
  const float* x    = (const float*)d_in[0];
  const int*   inst = (const int*)  d_in[1];
  const int*   tx   = (const int*)  d_in[2];
  const float* hx   = (const float*)d_in[3];
  const float* cx   = (const float*)d_in[4];
  const float* i1w  = (const float*)d_in[5];
  const float* i1b  = (const float*)d_in[6];
  const float* i2w  = (const float*)d_in[7];
  const float* i2b  = (const float*)d_in[8];
  const float* i3w  = (const float*)d_in[9];
  const float* i3b  = (const float*)d_in[10];
  const float* emb  = (const float*)d_in[11];
  const float* gwi  = (const float*)d_in[12];
  const float* gwh  = (const float*)d_in[13];
  const float* gbi  = (const float*)d_in[14];
  const float* gbh  = (const float*)d_in[15];
  const float* aw   = (const float*)d_in[16];
  const float* ab   = (const float*)d_in[17];
  const float* temb = (const float*)d_in[18];
  const float* lnw  = (const float*)d_in[19];
  const float* lnb  = (const float*)d_in[20];
  const float* lwi  = (const float*)d_in[21];
  const float* lwh  = (const float*)d_in[22];
  const float* lbi  = (const float*)d_in[23];
  const float* lbh  = (const float*)d_in[24];
  const float* cw   = (const float*)d_in[25];
  const float* cb   = (const float*)d_in[26];
  const float* acw  = (const float*)d_in[27];
  const float* acb  = (const float*)d_in[28];
  float* ws  = (float*)d_ws;
  float* out = (float*)d_out;

  a3c_pre <<<582, 256, 0, stream>>>(x, i1w, i1b, i2w, i2b, i3w, i3b,
                                    hx, lwh, lbh, tx, temb, cw, cb, acw, acb,
                                    inst, emb, gwi, gbi, gwh, ws, out);
  a3c_scan<<<1, 1024, 0, stream>>>(gbh, aw, ab, lnw, lnb, ws);
  a3c_post<<<4, 256, 0, stream>>>(lwi, lbi, cx, cw, acw, ws, out);
}

// Round 18
// 125.868 us; speedup vs baseline: 1.0229x; 1.0229x over previous
//
#include <hip/hip_runtime.h>
#include <math.h>

// ---------------------------------------------------------------------------
// A3C_LSTM_GA forward, batch=1.  FINAL = R10, the measured best (125.7us).
// Structure: single-CU GRU scan; weights as 24 asm-pinned f4 fragments that
// the compiler streams from L2 each step (~1.65us/step = single-CU L2 BW
// ceiling on 384KB).  17 rounds of counter evidence say this is the floor:
//   - VGPR grant law = min(256, 2048/(2*wavesPerWG)); demand>grant => silent
//     L2-remat (R9/R11/R13), so register residency of 384KB is impossible.
//   - LDS is a same-speed pipe; moving tiers there is neutral-to-worse
//     (R12/R15/R17).
//   - Multi-CU splits pay >=2us/step sync round trips (R1/R8) > the stream.
//  K1 a3c_pre (582 blocks x 256): b0 img MLP | b1-4 gates_h | b5 head-bias |
//     b6-197 gi f32 | b198-581 weight fragment pack
//  K2 a3c_scan (1 block x 1024): octet o owns rows [6o,6o+6); lane i cols
//     [32i,32i+32); 96 fdot2/thread/step; pp[768*9] partials; 2 barriers.
//  K3 a3c_post (4 blocks x 256): LSTM -> h/c -> head atomicAdd partials
// ---------------------------------------------------------------------------

typedef __fp16 h2 __attribute__((ext_vector_type(2)));
typedef __fp16 h8 __attribute__((ext_vector_type(8)));
typedef float  f4 __attribute__((ext_vector_type(4)));

// ws float offsets
#define WS_IMG    0        // 128
#define WS_GATESH 128      // 1024
#define WS_FUSED  1152     // 256
#define WS_GI     1408     // 64*768 f32
#define WS_REGW   50560    // 98304 float slots (196608 f16)  end=148864

__device__ __forceinline__ float dot4(const float4 a, const float4 b){
  return a.x*b.x + a.y*b.y + a.z*b.z + a.w*b.w;
}
__device__ __forceinline__ float sigm(float x){ return 1.f/(1.f+expf(-x)); }

#define P0(v) __builtin_shufflevector(v,v,0,1)
#define P1(v) __builtin_shufflevector(v,v,2,3)
#define P2(v) __builtin_shufflevector(v,v,4,5)
#define P3(v) __builtin_shufflevector(v,v,6,7)
#define PK(a,b) __builtin_amdgcn_cvt_pkrtz(a,b)
#define FD(w,e,acc) __builtin_amdgcn_fdot2(w,e,acc,false)

// ------------------------------------------------------------------- K1
__global__ __launch_bounds__(256) void a3c_pre(
    const float* __restrict__ x,
    const float* __restrict__ i1w, const float* __restrict__ i1b,
    const float* __restrict__ i2w, const float* __restrict__ i2b,
    const float* __restrict__ i3w, const float* __restrict__ i3b,
    const float* __restrict__ hx,  const float* __restrict__ lwh,
    const float* __restrict__ lbh,
    const int*   __restrict__ tx,  const float* __restrict__ temb,
    const float* __restrict__ cw,  const float* __restrict__ cb,
    const float* __restrict__ acw, const float* __restrict__ acb,
    const int*   __restrict__ inst, const float* __restrict__ emb,
    const float* __restrict__ gwi,  const float* __restrict__ gbi,
    const float* __restrict__ gwh,
    float* __restrict__ ws, float* __restrict__ out)
{
  const int b = blockIdx.x;
  const int t = threadIdx.x;

  if (b == 0) {
    // image MLP 400 -> 128 -> 128 -> 128
    __shared__ __align__(16) float x_lds[400];
    __shared__ __align__(16) float h1[128];
    __shared__ __align__(16) float h2s[128];
    x_lds[t] = x[t];
    if (t < 144) x_lds[256+t] = x[256+t];
    __syncthreads();
    {
      const int o = t>>1, half = t&1;
      const float4* wr = (const float4*)(i1w + o*400 + half*200);
      const float4* xr = (const float4*)(x_lds + half*200);
      float acc = 0.f;
      #pragma unroll 5
      for (int k=0;k<50;++k) acc += dot4(wr[k], xr[k]);
      acc += __shfl_down(acc, 1, 2);
      if (half == 0) h1[o] = fmaxf(acc + i1b[o], 0.f);
    }
    __syncthreads();
    if (t < 128){
      const float4* wr = (const float4*)(i2w + t*128);
      const float4* h4 = (const float4*)h1;
      float acc = i2b[t];
      #pragma unroll 8
      for (int k=0;k<32;++k) acc += dot4(wr[k], h4[k]);
      h2s[t] = fmaxf(acc, 0.f);
    }
    __syncthreads();
    if (t < 128){
      const float4* wr = (const float4*)(i3w + t*128);
      const float4* h4 = (const float4*)h2s;
      float acc = i3b[t];
      #pragma unroll 8
      for (int k=0;k<32;++k) acc += dot4(wr[k], h4[k]);
      ws[WS_IMG + t] = fmaxf(acc, 0.f);
    }

  } else if (b <= 4) {
    // gates_h = hx @ lstm_wh.T + lstm_bh
    __shared__ __align__(16) float hx_lds[256];
    hx_lds[t] = hx[t];
    __syncthreads();
    const int R = (b-1)*256 + t;
    const float4* wr = (const float4*)(lwh + R*256);
    const float4* h4 = (const float4*)hx_lds;
    float acc = lbh[R];
    #pragma unroll 8
    for (int k=0;k<64;++k) acc += dot4(wr[k], h4[k]);
    ws[WS_GATESH + R] = acc;

  } else if (b == 5) {
    // out[0..4] = bias + time-embedding partial of heads
    if (t < 64){
      float tv = 0.f;
      if (t < 32) tv = temb[tx[0]*32 + t];
      #pragma unroll
      for (int o=0;o<5;++o){
        const float* wrow = (o==0) ? cw : (acw + (o-1)*288);
        float pr = (t < 32) ? tv*wrow[256+t] : 0.f;
        #pragma unroll
        for (int off=16; off; off>>=1) pr += __shfl_down(pr, off, 32);
        if (t == 0) out[o] = pr + ((o==0) ? cb[0] : acb[o-1]);
      }
    }

  } else if (b < 198) {
    // gi[s][row] (f32): 192 blocks x 256 = 49152 = 64*768
    const int idx = (b-6)*256 + t;
    const int s = idx / 768;
    const int r = idx - s*768;
    const float4* wr = (const float4*)(gwi + r*32);
    const float4* er = (const float4*)(emb + inst[s]*32);
    float acc = gbi[r];
    #pragma unroll
    for (int k=0;k<8;++k) acc += dot4(wr[k], er[k]);
    ws[WS_GI + idx] = acc;

  } else {
    // regw: 384 blocks x 256 = 98304 h2 = 196608 f16, per-thread order:
    // thread tt = (octet o = tt>>3, lane i = tt&7) : rows 6o+rho (rho 0..5),
    // cols 32i + 8c + el (c 0..3, el 0..7); fragment index rho*4+c
    const int d = (b-198)*256 + t;      // h2 index
    const int e = d << 1;               // f16 index
    const int tt = e / 192;
    int rem = e - tt*192;
    const int rho = rem >> 5; rem &= 31;
    const int c = rem >> 3;
    const int el = rem & 7;
    const int row = 6*(tt>>3) + rho;
    const int col = ((tt&7)<<5) + (c<<3) + el;
    ((h2*)(ws + WS_REGW))[d] = PK(gwh[row*256+col], gwh[row*256+col+1]);
  }
}

// ------------------------------------------------------------------- K2
__global__ __attribute__((amdgpu_flat_work_group_size(1024,1024)))
void a3c_scan(
    const float* __restrict__ gbh,
    const float* __restrict__ aw,  const float* __restrict__ ab,
    const float* __restrict__ lnw, const float* __restrict__ lnb,
    float* __restrict__ ws)
{
  const int t = threadIdx.x;
  const int o = t >> 3, i = t & 7;

  __shared__ __align__(16) __fp16 h16[256];
  __shared__ float h32[256];
  __shared__ float pp[768*9];          // partials [row][9] (pad vs conflicts)
  __shared__ float bhl[768];
  __shared__ float gil[2][768];
  __shared__ __align__(16) float f0[128];

  if (t < 768){ bhl[t] = gbh[t]; gil[0][t] = ws[WS_GI + t]; }
  if (t < 256){ h16[t] = (__fp16)0.f; h32[t] = 0.f; }

  // 24 pinned fragments: rows 6o+rho, cols 32i+8c.. (+8); frag = rho*4+c
  const f4* rw = (const f4*)(ws + WS_REGW) + t*24;
  f4 W00=rw[0],  W01=rw[1],  W02=rw[2],  W03=rw[3];
  f4 W10=rw[4],  W11=rw[5],  W12=rw[6],  W13=rw[7];
  f4 W20=rw[8],  W21=rw[9],  W22=rw[10], W23=rw[11];
  f4 W30=rw[12], W31=rw[13], W32=rw[14], W33=rw[15];
  f4 W40=rw[16], W41=rw[17], W42=rw[18], W43=rw[19];
  f4 W50=rw[20], W51=rw[21], W52=rw[22], W53=rw[23];
  #define PIN(v) asm volatile("" : "+v"(v))
  PIN(W00);PIN(W01);PIN(W02);PIN(W03);PIN(W10);PIN(W11);PIN(W12);PIN(W13);
  PIN(W20);PIN(W21);PIN(W22);PIN(W23);PIN(W30);PIN(W31);PIN(W32);PIN(W33);
  PIN(W40);PIN(W41);PIN(W42);PIN(W43);PIN(W50);PIN(W51);PIN(W52);PIN(W53);
  #undef PIN
  __syncthreads();

  const int pbase = o*6;
  int cur = 0;
  for (int s=0; s<64; ++s){
    float gnx = 0.f;
    if (t < 768) gnx = ws[WS_GI + ((s<63)?(s+1):s)*768 + t];

    float a0=0.f,a1=0.f,a2=0.f,a3=0.f,a4=0.f,a5=0.f;
    #define CHUNK(c) { \
      const h8 hv = *(const h8*)(h16 + (i<<5) + ((c)<<3)); h8 w; \
      w=__builtin_bit_cast(h8,W0##c); \
      a0=FD(P0(w),P0(hv),a0); a0=FD(P1(w),P1(hv),a0); \
      a0=FD(P2(w),P2(hv),a0); a0=FD(P3(w),P3(hv),a0); \
      w=__builtin_bit_cast(h8,W1##c); \
      a1=FD(P0(w),P0(hv),a1); a1=FD(P1(w),P1(hv),a1); \
      a1=FD(P2(w),P2(hv),a1); a1=FD(P3(w),P3(hv),a1); \
      w=__builtin_bit_cast(h8,W2##c); \
      a2=FD(P0(w),P0(hv),a2); a2=FD(P1(w),P1(hv),a2); \
      a2=FD(P2(w),P2(hv),a2); a2=FD(P3(w),P3(hv),a2); \
      w=__builtin_bit_cast(h8,W3##c); \
      a3=FD(P0(w),P0(hv),a3); a3=FD(P1(w),P1(hv),a3); \
      a3=FD(P2(w),P2(hv),a3); a3=FD(P3(w),P3(hv),a3); \
      w=__builtin_bit_cast(h8,W4##c); \
      a4=FD(P0(w),P0(hv),a4); a4=FD(P1(w),P1(hv),a4); \
      a4=FD(P2(w),P2(hv),a4); a4=FD(P3(w),P3(hv),a4); \
      w=__builtin_bit_cast(h8,W5##c); \
      a5=FD(P0(w),P0(hv),a5); a5=FD(P1(w),P1(hv),a5); \
      a5=FD(P2(w),P2(hv),a5); a5=FD(P3(w),P3(hv),a5); }
    CHUNK(0) CHUNK(1) CHUNK(2) CHUNK(3)
    #undef CHUNK

    pp[(pbase+0)*9+i]=a0; pp[(pbase+1)*9+i]=a1; pp[(pbase+2)*9+i]=a2;
    pp[(pbase+3)*9+i]=a3; pp[(pbase+4)*9+i]=a4; pp[(pbase+5)*9+i]=a5;
    if (t < 768) gil[cur^1][t] = gnx;
    __syncthreads();
    if (t < 256){
      const float* pr = pp + t*9;
      const float* pz = pp + (256+t)*9;
      const float* pn = pp + (512+t)*9;
      float sr=bhl[t], sz=bhl[256+t], sn=bhl[512+t];
      #pragma unroll
      for (int k=0;k<8;++k){ sr+=pr[k]; sz+=pz[k]; sn+=pn[k]; }
      const float rr = sigm(gil[cur][t]       + sr);
      const float zz = sigm(gil[cur][256 + t] + sz);
      const float nn = tanhf(gil[cur][512 + t] + rr*sn);
      const float hv = (1.f - zz)*nn + zz*h32[t];
      h32[t] = hv;
      h16[t] = (__fp16)hv;
    }
    cur ^= 1;
    __syncthreads();
  }

  // ---- attention -> fuse -> lin (h_enc == h32)
  if (t < 128){
    const float4* wr = (const float4*)(aw + t*256);
    const float4* h4 = (const float4*)h32;
    float acc = ab[t];
    #pragma unroll 8
    for (int k=0;k<64;++k) acc += dot4(wr[k], h4[k]);
    f0[t] = ws[WS_IMG + t] * sigm(acc);
  }
  __syncthreads();
  if (t < 256){
    const float4* wr = (const float4*)(lnw + t*128);
    const float4* h4 = (const float4*)f0;
    float acc = lnb[t];
    #pragma unroll 8
    for (int k=0;k<32;++k) acc += dot4(wr[k], h4[k]);
    ws[WS_FUSED + t] = fmaxf(acc, 0.f);
  }
}

// ------------------------------------------------------------------- K3
__global__ __launch_bounds__(256) void a3c_post(
    const float* __restrict__ lwi, const float* __restrict__ lbi,
    const float* __restrict__ cx,
    const float* __restrict__ cw,  const float* __restrict__ acw,
    float* __restrict__ ws, float* __restrict__ out)
{
  const int p = blockIdx.x;            // 0..3, owns 64 LSTM units
  const int t = threadIdx.x;
  __shared__ __align__(16) float fused_lds[256];
  __shared__ float gv[256];
  __shared__ float hh[64];
  fused_lds[t] = ws[WS_FUSED + t];
  __syncthreads();
  const int g = t>>6, ul = t&63;
  const int R = (g<<8) + p*64 + ul;
  const float4* wr = (const float4*)(lwi + R*256);
  const float4* f4p = (const float4*)fused_lds;
  float acc = ws[WS_GATESH + R] + lbi[R];
  #pragma unroll 8
  for (int k=0;k<64;++k) acc += dot4(wr[k], f4p[k]);
  gv[t] = acc;
  __syncthreads();
  if (t < 64){
    const int u2 = p*64 + t;
    const float iv = gv[t], fv = gv[64+t], gg = gv[128+t], ov = gv[192+t];
    const float c = sigm(fv)*cx[u2] + sigm(iv)*tanhf(gg);
    const float h = sigm(ov)*tanhf(c);
    out[5   + u2] = h;
    out[261 + u2] = c;
    hh[t] = h;
  }
  __syncthreads();
  if (t < 64){
    #pragma unroll
    for (int o=0;o<5;++o){
      const float* wrow = (o==0) ? cw : (acw + (o-1)*288);
      float pr = hh[t]*wrow[p*64 + t];
      #pragma unroll
      for (int off=32; off; off>>=1) pr += __shfl_down(pr, off, 64);
      if (t == 0) atomicAdd(out + o, pr);
    }
  }
}

extern "C" void kernel_launch(void* const* d_in, const int* in_sizes, int n_in,
                              void* d_out, int out_size, void* d_ws, size_t ws_size,
                              hipStream_t stream) {
  (void)in_sizes; (void)n_in; (void)out_size; (void)ws_size;
  const float* x    = (const float*)d_in[0];
  const int*   inst = (const int*)  d_in[1];
  const int*   tx   = (const int*)  d_in[2];
  const float* hx   = (const float*)d_in[3];
  const float* cx   = (const float*)d_in[4];
  const float* i1w  = (const float*)d_in[5];
  const float* i1b  = (const float*)d_in[6];
  const float* i2w  = (const float*)d_in[7];
  const float* i2b  = (const float*)d_in[8];
  const float* i3w  = (const float*)d_in[9];
  const float* i3b  = (const float*)d_in[10];
  const float* emb  = (const float*)d_in[11];
  const float* gwi  = (const float*)d_in[12];
  const float* gwh  = (const float*)d_in[13];
  const float* gbi  = (const float*)d_in[14];
  const float* gbh  = (const float*)d_in[15];
  const float* aw   = (const float*)d_in[16];
  const float* ab   = (const float*)d_in[17];
  const float* temb = (const float*)d_in[18];
  const float* lnw  = (const float*)d_in[19];
  const float* lnb  = (const float*)d_in[20];
  const float* lwi  = (const float*)d_in[21];
  const float* lwh  = (const float*)d_in[22];
  const float* lbi  = (const float*)d_in[23];
  const float* lbh  = (const float*)d_in[24];
  const float* cw   = (const float*)d_in[25];
  const float* cb   = (const float*)d_in[26];
  const float* acw  = (const float*)d_in[27];
  const float* acb  = (const float*)d_in[28];
  float* ws  = (float*)d_ws;
  float* out = (float*)d_out;

  a3c_pre <<<582, 256, 0, stream>>>(x, i1w, i1b, i2w, i2b, i3w, i3b,
                                    hx, lwh, lbh, tx, temb, cw, cb, acw, acb,
                                    inst, emb, gwi, gbi, gwh, ws, out);
  a3c_scan<<<1, 1024, 0, stream>>>(gbh, aw, ab, lnw, lnb, ws);
  a3c_post<<<4, 256, 0, stream>>>(lwi, lbi, cx, cw, acw, ws, out);
}